// Round 1
// baseline (431.089 us; speedup 1.0000x reference)
//
#include <hip/hip_runtime.h>

#define XL 432
#define YL 496
#define BN 4
#define COUT 64
#define PP 32

// Pass 1: resolve scatter collisions — highest pillar index wins (numpy
// last-write-wins semantics for duplicate (b,y,x) cells).
__global__ __launch_bounds__(256) void winner_kernel(const int* __restrict__ coors,
                                                     int* __restrict__ winner, int M) {
    int m = blockIdx.x * blockDim.x + threadIdx.x;
    if (m >= M) return;
    int b = coors[4 * m + 0];
    int y = coors[4 * m + 2];
    int x = coors[4 * m + 3];
    if (x < 0 || x >= XL || y < 0 || y >= YL) return;
    atomicMax(&winner[(b * YL + y) * XL + x], m);
}

// Pass 2: per pillar — augment features, 9->64 matvec, BN+ReLU, max-pool
// over points, scatter the winning pillar's 64 channels into the canvas.
// One 64-lane slice per pillar (lane == output channel), 4 pillars/block.
__global__ __launch_bounds__(256) void pillar_kernel(
    const float* __restrict__ pillars,  // (M, 32, 4)
    const int* __restrict__ coors,      // (M, 4)
    const int* __restrict__ nums,       // (M,)
    const float* __restrict__ W,        // (64, 9)
    const float* __restrict__ gamma, const float* __restrict__ beta,
    const float* __restrict__ rmean, const float* __restrict__ rvar,
    const int* __restrict__ winner,     // (4, 496, 432)
    float* __restrict__ out,            // (4, 64, 496, 432)
    int M) {
    const int pb   = threadIdx.x >> 6;   // pillar slot in block, 0..3
    const int lane = threadIdx.x & 63;   // output channel
    const int m    = blockIdx.x * 4 + pb;

    __shared__ float4 pts[4][PP];        // 2 KB: staged point data

    if (m < M && lane < PP) {
        pts[pb][lane] = ((const float4*)pillars)[m * PP + lane];
    }
    __syncthreads();
    if (m >= M) return;

    const int b = coors[4 * m + 0];
    const int y = coors[4 * m + 2];
    const int x = coors[4 * m + 3];
    if (x < 0 || x >= XL || y < 0 || y >= YL) return;
    const int cell = (b * YL + y) * XL + x;
    if (winner[cell] != m) return;       // lost the collision -> dropped

    int num = nums[m];
    if (num < 1) num = 1;
    if (num > PP) num = PP;

    // per-channel BN affine
    const float scale = gamma[lane] * rsqrtf(rvar[lane] + 1e-3f);
    const float bias  = beta[lane] - rmean[lane] * scale;

    // mean over valid points (LDS same-address broadcast, conflict-free)
    float sx = 0.f, sy = 0.f, sz = 0.f;
    for (int p = 0; p < num; ++p) {
        float4 q = pts[pb][p];
        sx += q.x; sy += q.y; sz += q.z;
    }
    const float inv = 1.0f / (float)num;
    const float mx = sx * inv, my = sy * inv, mz = sz * inv;

    const float xc = (float)x * 0.16f + 0.08f;
    const float yc = (float)y * 0.16f + (0.08f - 39.68f);

    // W row for this channel
    const float w0 = W[lane * 9 + 0], w1 = W[lane * 9 + 1], w2 = W[lane * 9 + 2];
    const float w3 = W[lane * 9 + 3], w4 = W[lane * 9 + 4], w5 = W[lane * 9 + 5];
    const float w6 = W[lane * 9 + 6], w7 = W[lane * 9 + 7], w8 = W[lane * 9 + 8];

    // masked points (p >= num) contribute relu(0*scale + bias) = max(bias, 0)
    float acc = (num < PP) ? fmaxf(bias, 0.0f) : 0.0f;

    for (int p = 0; p < num; ++p) {
        float4 q = pts[pb][p];
        float h = q.x * w0 + q.y * w1 + q.z * w2 + q.w * w3
                + (q.x - mx) * w4 + (q.y - my) * w5 + (q.z - mz) * w6
                + (q.x - xc) * w7 + (q.y - yc) * w8;
        float v = h * scale + bias;
        acc = fmaxf(acc, fmaxf(v, 0.0f));
    }

    // out[b, lane, y, x]
    out[((b * COUT + lane) * YL + y) * XL + x] = acc;
}

extern "C" void kernel_launch(void* const* d_in, const int* in_sizes, int n_in,
                              void* d_out, int out_size, void* d_ws, size_t ws_size,
                              hipStream_t stream) {
    const float* pillars = (const float*)d_in[0];
    const int*   coors   = (const int*)d_in[1];
    const int*   nums    = (const int*)d_in[2];
    const float* W       = (const float*)d_in[3];
    const float* gamma   = (const float*)d_in[4];
    const float* beta    = (const float*)d_in[5];
    const float* rmean   = (const float*)d_in[6];
    const float* rvar    = (const float*)d_in[7];
    float* out = (float*)d_out;

    const int M = in_sizes[2];           // nums has M elements
    int* winner = (int*)d_ws;            // (4, 496, 432) ints = 3.43 MB

    // zero canvas; winner = -1 (0xFFFFFFFF)
    hipMemsetAsync(out, 0, (size_t)out_size * sizeof(float), stream);
    hipMemsetAsync(winner, 0xFF, (size_t)BN * YL * XL * sizeof(int), stream);

    winner_kernel<<<(M + 255) / 256, 256, 0, stream>>>(coors, winner, M);
    pillar_kernel<<<(M + 3) / 4, 256, 0, stream>>>(
        pillars, coors, nums, W, gamma, beta, rmean, rvar, winner, out, M);
}

// Round 3
// 412.457 us; speedup vs baseline: 1.0452x; 1.0452x over previous
//
#include <hip/hip_runtime.h>

#define XL 432
#define XL4 108          // XL/4
#define YL 496
#define BN 4
#define COUT 64
#define PP 32

// Pass 1: resolve scatter collisions — highest pillar index wins (numpy
// last-write-wins semantics for duplicate (b,y,x) cells).
__global__ __launch_bounds__(256) void winner_kernel(const int* __restrict__ coors,
                                                     int* __restrict__ winner, int M) {
    int m = blockIdx.x * blockDim.x + threadIdx.x;
    if (m >= M) return;
    int b = coors[4 * m + 0];
    int y = coors[4 * m + 2];
    int x = coors[4 * m + 3];
    if (x < 0 || x >= XL || y < 0 || y >= YL) return;
    atomicMax(&winner[(b * YL + y) * XL + x], m);
}

// Pass 2: per pillar — augment features, 9->64 matvec, BN+ReLU, max-pool
// over points. Write the 64-channel pooled vector COMPACTLY (coalesced) to
// pooled[m*64+c]; the dense canvas pass gathers from it. One 64-lane slice
// per pillar (lane == output channel), 4 pillars per 256-thread block.
__global__ __launch_bounds__(256) void pillar_compute(
    const float* __restrict__ pillars,  // (M, 32, 4)
    const int* __restrict__ coors,      // (M, 4)
    const int* __restrict__ nums,       // (M,)
    const float* __restrict__ W,        // (64, 9)
    const float* __restrict__ gamma, const float* __restrict__ beta,
    const float* __restrict__ rmean, const float* __restrict__ rvar,
    float* __restrict__ pooled,         // (M, 64)
    int M) {
    const int pb   = threadIdx.x >> 6;   // pillar slot in block, 0..3
    const int lane = threadIdx.x & 63;   // output channel
    const int m    = blockIdx.x * 4 + pb;

    __shared__ float4 pts[4][PP];        // 2 KB staged point data

    if (m < M && lane < PP) {
        pts[pb][lane] = ((const float4*)pillars)[m * PP + lane];
    }
    __syncthreads();
    if (m >= M) return;

    const int x = coors[4 * m + 3];
    const int y = coors[4 * m + 2];

    int num = nums[m];
    if (num < 1) num = 1;
    if (num > PP) num = PP;

    // per-channel BN affine
    const float scale = gamma[lane] * rsqrtf(rvar[lane] + 1e-3f);
    const float bias  = beta[lane] - rmean[lane] * scale;

    // mean over valid points (LDS same-address broadcast, conflict-free)
    float sx = 0.f, sy = 0.f, sz = 0.f;
    for (int p = 0; p < num; ++p) {
        float4 q = pts[pb][p];
        sx += q.x; sy += q.y; sz += q.z;
    }
    const float inv = 1.0f / (float)num;
    const float mx = sx * inv, my = sy * inv, mz = sz * inv;

    const float xc = (float)x * 0.16f + 0.08f;
    const float yc = (float)y * 0.16f + (0.08f - 39.68f);

    const float w0 = W[lane * 9 + 0], w1 = W[lane * 9 + 1], w2 = W[lane * 9 + 2];
    const float w3 = W[lane * 9 + 3], w4 = W[lane * 9 + 4], w5 = W[lane * 9 + 5];
    const float w6 = W[lane * 9 + 6], w7 = W[lane * 9 + 7], w8 = W[lane * 9 + 8];

    // masked points (p >= num) contribute relu(0*scale + bias) = max(bias, 0)
    float acc = (num < PP) ? fmaxf(bias, 0.0f) : 0.0f;

    for (int p = 0; p < num; ++p) {
        float4 q = pts[pb][p];
        float h = q.x * w0 + q.y * w1 + q.z * w2 + q.w * w3
                + (q.x - mx) * w4 + (q.y - my) * w5 + (q.z - mz) * w6
                + (q.x - xc) * w7 + (q.y - yc) * w8;
        float v = h * scale + bias;
        acc = fmaxf(acc, fmaxf(v, 0.0f));
    }

    pooled[m * COUT + lane] = acc;      // coalesced 256B per wave
}

// Pass 3: dense canvas write — replaces the memset. Each thread owns 4
// consecutive x of one (b,y); loads 4 winners as int4, then stores one
// float4 per channel (64 stores, 16B/lane coalesced).
// NOTE: "all empty" is the AND of sign bits (R2 bug: OR zero-filled any
// group containing a single empty cell, dropping real winners).
__global__ __launch_bounds__(256) void canvas_kernel(
    const int* __restrict__ winner,     // (BN, YL, XL)
    const float* __restrict__ pooled,   // (M, 64)
    float4* __restrict__ out4) {        // (BN, 64, YL, XL) as float4
    const int tid = blockIdx.x * blockDim.x + threadIdx.x;  // over BN*YL*XL4
    if (tid >= BN * YL * XL4) return;

    const int b   = tid / (YL * XL4);
    const int rem = tid - b * (YL * XL4);
    const int y   = rem / XL4;
    const int xq  = rem - y * XL4;

    const int4 w = ((const int4*)winner)[tid];

    // out4 index for (b, c, y, x=4*xq): ((b*COUT+c)*YL + y)*XL4 + xq
    long base = ((long)b * COUT * YL + y) * XL4 + xq;
    const long cstride = (long)YL * XL4;

    if ((w.x & w.y & w.z & w.w) < 0) {
        // ALL four cells empty: pure zero fill
        const float4 z = make_float4(0.f, 0.f, 0.f, 0.f);
        #pragma unroll 8
        for (int c = 0; c < COUT; ++c) {
            out4[base + c * cstride] = z;
        }
    } else {
        // clamp negative winners to 0 so pointers stay in-bounds; value is
        // selected by predicate so the clamp never leaks data.
        const float* p0 = pooled + (long)(w.x >= 0 ? w.x : 0) * COUT;
        const float* p1 = pooled + (long)(w.y >= 0 ? w.y : 0) * COUT;
        const float* p2 = pooled + (long)(w.z >= 0 ? w.z : 0) * COUT;
        const float* p3 = pooled + (long)(w.w >= 0 ? w.w : 0) * COUT;
        #pragma unroll 8
        for (int c = 0; c < COUT; ++c) {
            float4 v;
            v.x = (w.x >= 0) ? p0[c] : 0.f;
            v.y = (w.y >= 0) ? p1[c] : 0.f;
            v.z = (w.z >= 0) ? p2[c] : 0.f;
            v.w = (w.w >= 0) ? p3[c] : 0.f;
            out4[base + c * cstride] = v;
        }
    }
}

extern "C" void kernel_launch(void* const* d_in, const int* in_sizes, int n_in,
                              void* d_out, int out_size, void* d_ws, size_t ws_size,
                              hipStream_t stream) {
    const float* pillars = (const float*)d_in[0];
    const int*   coors   = (const int*)d_in[1];
    const int*   nums    = (const int*)d_in[2];
    const float* W       = (const float*)d_in[3];
    const float* gamma   = (const float*)d_in[4];
    const float* beta    = (const float*)d_in[5];
    const float* rmean   = (const float*)d_in[6];
    const float* rvar    = (const float*)d_in[7];
    float* out = (float*)d_out;

    const int M = in_sizes[2];                       // nums has M elements
    int*   winner = (int*)d_ws;                      // (4,496,432) = 3.43 MB
    float* pooled = (float*)((char*)d_ws + (size_t)BN * YL * XL * sizeof(int)); // (M,64) = 16.4 MB

    hipMemsetAsync(winner, 0xFF, (size_t)BN * YL * XL * sizeof(int), stream);

    winner_kernel<<<(M + 255) / 256, 256, 0, stream>>>(coors, winner, M);
    pillar_compute<<<(M + 3) / 4, 256, 0, stream>>>(
        pillars, coors, nums, W, gamma, beta, rmean, rvar, pooled, M);
    const int cells4 = BN * YL * XL4;
    canvas_kernel<<<(cells4 + 255) / 256, 256, 0, stream>>>(winner, pooled, (float4*)out);
}

// Round 4
// 305.495 us; speedup vs baseline: 1.4111x; 1.3501x over previous
//
#include <hip/hip_runtime.h>

#define XL 432
#define XL4 108          // XL/4
#define YL 496
#define CELLS_B (YL * XL)     // 214272 cells per batch
#define PLANE4 (CELLS_B / 4)  // 53568 float4-groups per (b,c) plane
#define BN 4
#define COUT 64
#define PP 32
#define TCELLS 128       // cells per canvas block
#define TG 32            // float4-groups per canvas block
#define LSTR 132         // LDS row stride (dwords): %4==0 (b128-aligned), ≡4 (mod 32)

// Pass 1: resolve scatter collisions — highest pillar index wins (numpy
// last-write-wins semantics for duplicate (b,y,x) cells).
__global__ __launch_bounds__(256) void winner_kernel(const int* __restrict__ coors,
                                                     int* __restrict__ winner, int M) {
    int m = blockIdx.x * blockDim.x + threadIdx.x;
    if (m >= M) return;
    int b = coors[4 * m + 0];
    int y = coors[4 * m + 2];
    int x = coors[4 * m + 3];
    if (x < 0 || x >= XL || y < 0 || y >= YL) return;
    atomicMax(&winner[(b * YL + y) * XL + x], m);
}

// Pass 2: per pillar — augment features, 9->64 matvec, BN+ReLU, max-pool
// over points. Pooled 64-vector written compactly (coalesced) to pooled[m].
__global__ __launch_bounds__(256) void pillar_compute(
    const float* __restrict__ pillars,  // (M, 32, 4)
    const int* __restrict__ coors,      // (M, 4)
    const int* __restrict__ nums,       // (M,)
    const float* __restrict__ W,        // (64, 9)
    const float* __restrict__ gamma, const float* __restrict__ beta,
    const float* __restrict__ rmean, const float* __restrict__ rvar,
    float* __restrict__ pooled,         // (M, 64)
    int M) {
    const int pb   = threadIdx.x >> 6;   // pillar slot in block, 0..3
    const int lane = threadIdx.x & 63;   // output channel
    const int m    = blockIdx.x * 4 + pb;

    __shared__ float4 pts[4][PP];

    if (m < M && lane < PP) {
        pts[pb][lane] = ((const float4*)pillars)[m * PP + lane];
    }
    __syncthreads();
    if (m >= M) return;

    const int x = coors[4 * m + 3];
    const int y = coors[4 * m + 2];

    int num = nums[m];
    if (num < 1) num = 1;
    if (num > PP) num = PP;

    const float scale = gamma[lane] * rsqrtf(rvar[lane] + 1e-3f);
    const float bias  = beta[lane] - rmean[lane] * scale;

    float sx = 0.f, sy = 0.f, sz = 0.f;
    for (int p = 0; p < num; ++p) {
        float4 q = pts[pb][p];
        sx += q.x; sy += q.y; sz += q.z;
    }
    const float inv = 1.0f / (float)num;
    const float mx = sx * inv, my = sy * inv, mz = sz * inv;

    const float xc = (float)x * 0.16f + 0.08f;
    const float yc = (float)y * 0.16f + (0.08f - 39.68f);

    const float w0 = W[lane * 9 + 0], w1 = W[lane * 9 + 1], w2 = W[lane * 9 + 2];
    const float w3 = W[lane * 9 + 3], w4 = W[lane * 9 + 4], w5 = W[lane * 9 + 5];
    const float w6 = W[lane * 9 + 6], w7 = W[lane * 9 + 7], w8 = W[lane * 9 + 8];

    // masked points (p >= num) contribute relu(0*scale + bias) = max(bias, 0)
    float acc = (num < PP) ? fmaxf(bias, 0.0f) : 0.0f;

    for (int p = 0; p < num; ++p) {
        float4 q = pts[pb][p];
        float h = q.x * w0 + q.y * w1 + q.z * w2 + q.w * w3
                + (q.x - mx) * w4 + (q.y - my) * w5 + (q.z - mz) * w6
                + (q.x - xc) * w7 + (q.y - yc) * w8;
        float v = h * scale + bias;
        acc = fmaxf(acc, fmaxf(v, 0.0f));
    }

    pooled[m * COUT + lane] = acc;
}

// Pass 3: dense canvas write, gather->LDS-transpose->store.
// Block = 256 threads, 128 consecutive cells of one batch.
// Phase 1: 2 threads per cell read the winner's pooled row coalesced
//   (8 float4 each) and scatter scalars into lds[channel*LSTR + cell]
//   (bank = (4k+i+cell) mod 32 -> 2 lanes/bank = conflict-free).
// Phase 2: thread (chi, xg) stores float4 over x for 8 channels; LDS read
//   is contiguous-per-lane ds_read_b128 (conflict-free), store coalesced.
__global__ __launch_bounds__(256) void canvas_kernel(
    const int* __restrict__ winner,     // (BN, YL, XL)
    const float* __restrict__ pooled,   // (M, 64)
    float4* __restrict__ out4) {        // (BN, 64, YL*XL/4)
    __shared__ float lds[COUT * LSTR];  // 33792 B

    const int t   = threadIdx.x;
    const int b   = blockIdx.y;
    const int blk = blockIdx.x;         // 0..1673
    const int baseCell = blk * TCELLS;

    // ---- phase 1: gather pooled rows into LDS ----
    {
        const int cell = t >> 1;        // 0..127
        const int h    = t & 1;         // half of the 64-channel row
        const int w = winner[b * CELLS_B + baseCell + cell];

        float4 r[8];
        if (w >= 0) {
            const float4* row = (const float4*)(pooled + (size_t)w * COUT) + h * 8;
            #pragma unroll
            for (int k = 0; k < 8; ++k) r[k] = row[k];
        } else {
            #pragma unroll
            for (int k = 0; k < 8; ++k) r[k] = make_float4(0.f, 0.f, 0.f, 0.f);
        }
        #pragma unroll
        for (int k = 0; k < 8; ++k) {
            const int cb = h * 32 + 4 * k;
            lds[(cb + 0) * LSTR + cell] = r[k].x;
            lds[(cb + 1) * LSTR + cell] = r[k].y;
            lds[(cb + 2) * LSTR + cell] = r[k].z;
            lds[(cb + 3) * LSTR + cell] = r[k].w;
        }
    }
    __syncthreads();

    // ---- phase 2: coalesced float4 stores ----
    {
        const int xg  = t & 31;         // group within block's 32
        const int chi = t >> 5;         // 0..7
        float4* outb = out4 + (size_t)b * COUT * PLANE4 + (size_t)blk * TG + xg;
        #pragma unroll
        for (int cc = 0; cc < 8; ++cc) {
            const int c = cc * 8 + chi;
            const float4 v = *(const float4*)&lds[c * LSTR + 4 * xg];
            outb[(size_t)c * PLANE4] = v;
        }
    }
}

extern "C" void kernel_launch(void* const* d_in, const int* in_sizes, int n_in,
                              void* d_out, int out_size, void* d_ws, size_t ws_size,
                              hipStream_t stream) {
    const float* pillars = (const float*)d_in[0];
    const int*   coors   = (const int*)d_in[1];
    const int*   nums    = (const int*)d_in[2];
    const float* W       = (const float*)d_in[3];
    const float* gamma   = (const float*)d_in[4];
    const float* beta    = (const float*)d_in[5];
    const float* rmean   = (const float*)d_in[6];
    const float* rvar    = (const float*)d_in[7];
    float* out = (float*)d_out;

    const int M = in_sizes[2];                       // nums has M elements
    int*   winner = (int*)d_ws;                      // (4,496,432) = 3.43 MB
    float* pooled = (float*)((char*)d_ws + (size_t)BN * CELLS_B * sizeof(int)); // (M,64)

    hipMemsetAsync(winner, 0xFF, (size_t)BN * CELLS_B * sizeof(int), stream);

    winner_kernel<<<(M + 255) / 256, 256, 0, stream>>>(coors, winner, M);
    pillar_compute<<<(M + 3) / 4, 256, 0, stream>>>(
        pillars, coors, nums, W, gamma, beta, rmean, rvar, pooled, M);

    dim3 cgrid(CELLS_B / TCELLS, BN);   // (1674, 4)
    canvas_kernel<<<cgrid, 256, 0, stream>>>(winner, pooled, (float4*)out);
}

// Round 6
// 298.880 us; speedup vs baseline: 1.4423x; 1.0221x over previous
//
#include <hip/hip_runtime.h>

#define XL 432
#define YL 496
#define CELLS_B (YL * XL)     // 214272 cells per batch
#define PLANE4 (CELLS_B / 4)  // 53568 float4-groups per (b,c) plane
#define BN 4
#define COUT 64
#define PP 32
#define TCELLS 128       // cells per canvas block
#define TG 32            // float4-groups per canvas block
#define LSTR 132         // LDS row stride (dwords): %4==0 (b128-aligned), ≡4 (mod 32)

typedef float v4f __attribute__((ext_vector_type(4)));  // native vec for nontemporal builtins

// Pass 1: resolve scatter collisions — highest pillar index wins (numpy
// last-write-wins semantics for duplicate (b,y,x) cells).
__global__ __launch_bounds__(256) void winner_kernel(const int* __restrict__ coors,
                                                     int* __restrict__ winner, int M) {
    int m = blockIdx.x * blockDim.x + threadIdx.x;
    if (m >= M) return;
    const int4 c = ((const int4*)coors)[m];
    if (c.w < 0 || c.w >= XL || c.z < 0 || c.z >= YL) return;
    atomicMax(&winner[(c.x * YL + c.z) * XL + c.w], m);
}

// Pass 2: per winning pillar — folded 9->64 matvec + BN + ReLU + max-pool.
// h_p = q_p . cw - C0 with cw = (w0+w4+w7, w1+w5+w8, w2+w6, w3),
// C0 = mean.(w4,w5,w6) + xc*w7 + yc*w8. BN affine is monotone per channel,
// so pooled = affine(scale>=0 ? max_p dot : min_p dot). Single loop pass.
__global__ __launch_bounds__(256) void pillar_compute(
    const float* __restrict__ pillars,  // (M, 32, 4)
    const int* __restrict__ coors,      // (M, 4)
    const int* __restrict__ nums,       // (M,)
    const float* __restrict__ W,        // (64, 9)
    const float* __restrict__ gamma, const float* __restrict__ beta,
    const float* __restrict__ rmean, const float* __restrict__ rvar,
    const int* __restrict__ winner,     // (BN, YL, XL)
    float* __restrict__ pooled,         // (M, 64)
    int M) {
    const int pb   = threadIdx.x >> 6;   // pillar slot in block, 0..3
    const int lane = threadIdx.x & 63;   // output channel
    const int m    = blockIdx.x * 4 + pb;

    __shared__ float4 pts[4][PP];

    if (m < M && lane < PP) {
        pts[pb][lane] = ((const float4*)pillars)[m * PP + lane];
    }
    __syncthreads();
    if (m >= M) return;

    const int4 co = ((const int4*)coors)[m];
    const int x = co.w, y = co.z;
    if (x < 0 || x >= XL || y < 0 || y >= YL) return;        // dropped
    if (winner[(co.x * YL + y) * XL + x] != m) return;       // lost collision

    int num = nums[m];
    if (num < 1) num = 1;
    if (num > PP) num = PP;

    const float scale = gamma[lane] * rsqrtf(rvar[lane] + 1e-3f);
    const float bias  = beta[lane] - rmean[lane] * scale;

    const float w0 = W[lane * 9 + 0], w1 = W[lane * 9 + 1], w2 = W[lane * 9 + 2];
    const float w3 = W[lane * 9 + 3], w4 = W[lane * 9 + 4], w5 = W[lane * 9 + 5];
    const float w6 = W[lane * 9 + 6], w7 = W[lane * 9 + 7], w8 = W[lane * 9 + 8];
    const float cwx = w0 + w4 + w7, cwy = w1 + w5 + w8, cwz = w2 + w6, cww = w3;

    float sx = 0.f, sy = 0.f, sz = 0.f;
    float dmax = -3.0e38f, dmin = 3.0e38f;
    for (int p = 0; p < num; ++p) {
        const float4 q = pts[pb][p];          // same-address broadcast
        sx += q.x; sy += q.y; sz += q.z;
        const float d = q.x * cwx + q.y * cwy + q.z * cwz + q.w * cww;
        dmax = fmaxf(dmax, d);
        dmin = fminf(dmin, d);
    }
    const float inv = 1.0f / (float)num;
    const float xc = (float)x * 0.16f + 0.08f;
    const float yc = (float)y * 0.16f + (0.08f - 39.68f);
    const float C0 = sx * inv * w4 + sy * inv * w5 + sz * inv * w6
                   + xc * w7 + yc * w8;

    const float sel = (scale >= 0.f) ? dmax : dmin;
    float v = (sel - C0) * scale + bias;
    if (num < PP) v = fmaxf(v, bias);         // masked points give relu(bias)
    pooled[m * COUT + lane] = fmaxf(v, 0.f);
}

// Pass 3: dense canvas write, gather->LDS-transpose->store. 512 threads,
// 128 cells/block (32 waves/CU). Phase 1: 4 threads per cell, thread qq
// reads the winner row's float4 chunks {qq, qq+4, qq+8, qq+12} (64B each,
// covering 256B together) and scatters scalars to lds[row*LSTR+cell] —
// bank = (16qq + 4comp + cell) mod 32 -> 2 lanes/bank (free). Phase 2:
// thread (chi, xg) nontemporal-stores float4 runs over x for 4 channels.
__global__ __launch_bounds__(512) void canvas_kernel(
    const int* __restrict__ winner,     // (BN, YL, XL)
    const float* __restrict__ pooled,   // (M, 64)
    v4f* __restrict__ out4) {           // (BN, 64, YL*XL/4)
    __shared__ float lds[COUT * LSTR];  // 33792 B -> 4 blocks/CU

    const int t   = threadIdx.x;
    const int b   = blockIdx.y;
    const int blk = blockIdx.x;         // 0..1673
    const int baseCell = blk * TCELLS;

    // ---- phase 1: gather pooled rows into LDS ----
    {
        const int cell = t >> 2;        // 0..127
        const int qq   = t & 3;
        const int w = winner[b * CELLS_B + baseCell + cell];

        float4 r[4];
        if (w >= 0) {
            const float4* row = (const float4*)(pooled + (size_t)w * COUT);
            #pragma unroll
            for (int k = 0; k < 4; ++k) r[k] = row[qq + 4 * k];
        } else {
            #pragma unroll
            for (int k = 0; k < 4; ++k) r[k] = make_float4(0.f, 0.f, 0.f, 0.f);
        }
        #pragma unroll
        for (int k = 0; k < 4; ++k) {
            const int cb = 4 * (qq + 4 * k);   // channel base of this chunk
            lds[(cb + 0) * LSTR + cell] = r[k].x;
            lds[(cb + 1) * LSTR + cell] = r[k].y;
            lds[(cb + 2) * LSTR + cell] = r[k].z;
            lds[(cb + 3) * LSTR + cell] = r[k].w;
        }
    }
    __syncthreads();

    // ---- phase 2: coalesced nontemporal float4 stores ----
    {
        const int xg  = t & 31;         // group within block's 32
        const int chi = t >> 5;         // 0..15
        v4f* outb = out4 + (size_t)b * COUT * PLANE4 + (size_t)blk * TG + xg;
        #pragma unroll
        for (int cc = 0; cc < 4; ++cc) {
            const int c = cc * 16 + chi;
            const v4f v = *(const v4f*)&lds[c * LSTR + 4 * xg];
            __builtin_nontemporal_store(v, &outb[(size_t)c * PLANE4]);
        }
    }
}

extern "C" void kernel_launch(void* const* d_in, const int* in_sizes, int n_in,
                              void* d_out, int out_size, void* d_ws, size_t ws_size,
                              hipStream_t stream) {
    const float* pillars = (const float*)d_in[0];
    const int*   coors   = (const int*)d_in[1];
    const int*   nums    = (const int*)d_in[2];
    const float* W       = (const float*)d_in[3];
    const float* gamma   = (const float*)d_in[4];
    const float* beta    = (const float*)d_in[5];
    const float* rmean   = (const float*)d_in[6];
    const float* rvar    = (const float*)d_in[7];
    float* out = (float*)d_out;

    const int M = in_sizes[2];                       // nums has M elements
    int*   winner = (int*)d_ws;                      // (4,496,432) = 3.43 MB
    float* pooled = (float*)((char*)d_ws + (size_t)BN * CELLS_B * sizeof(int)); // (M,64)

    (void)hipMemsetAsync(winner, 0xFF, (size_t)BN * CELLS_B * sizeof(int), stream);

    winner_kernel<<<(M + 255) / 256, 256, 0, stream>>>(coors, winner, M);
    pillar_compute<<<(M + 3) / 4, 256, 0, stream>>>(
        pillars, coors, nums, W, gamma, beta, rmean, rvar, winner, pooled, M);

    dim3 cgrid(CELLS_B / TCELLS, BN);   // (1674, 4)
    canvas_kernel<<<cgrid, 512, 0, stream>>>(winner, pooled, (v4f*)out);
}